// Round 1
// baseline (21752.740 us; speedup 1.0000x reference)
//
#include <hip/hip_runtime.h>

#define NTOKS 3152      // B*T*P = 2*8*197
#define DMODEL 384
#define EDIM 768
#define TWOE 1536
#define SDIM 16
#define RDIM 24
#define XDIM 56         // R + 2S
#define NLAYER 12

__device__ __forceinline__ float em_silu(float v) { return v / (1.f + __expf(-v)); }

// ---------------- patch embed + cls + pos embed + temporal sin/cos enc ----------------
__global__ __launch_bounds__(DMODEL)
void em_patch_embed(const float* __restrict__ x, const float* __restrict__ pw,
                    const float* __restrict__ pb, const float* __restrict__ cls,
                    const float* __restrict__ pos, float* __restrict__ hidden) {
  const int tok = blockIdx.x;          // (b*T+t)*P + p
  const int d = threadIdx.x;
  const int p = tok % 197;
  const int bt = tok / 197;
  const int t = bt % 8;
  const int b = bt / 8;
  if (p == 0) {
    hidden[(size_t)tok * DMODEL + d] = cls[d] + pos[d];
    return;
  }
  __shared__ float patch[768];         // 3 channels * 16*16 pixels
  const int np = p - 1;
  const int hp = np / 14, wp = np % 14;
  for (int i = d; i < 768; i += DMODEL) {
    const int c = i >> 8;
    const int rem = i & 255;
    const int ph = rem >> 4, pwx = rem & 15;
    patch[i] = x[(((size_t)(b * 3 + c) * 8 + t) * 224 + (hp * 16 + ph)) * 224 + (wp * 16 + pwx)];
  }
  __syncthreads();
  float acc = pb[d];
  const float* wrow = pw + (size_t)d * 768;
  #pragma unroll 8
  for (int k = 0; k < 768; ++k) acc += patch[k] * wrow[k];
  // temporal encoding: even d -> sin(t/div), odd d -> cos(t/div), div = 10000^((d - d%2)/384)
  const float div = powf(10000.f, (float)(d & ~1) * (1.f / 384.f));
  const float ang = (float)t / div;
  const float enc = (d & 1) ? cosf(ang) : sinf(ang);
  hidden[(size_t)tok * DMODEL + d] = acc + pos[(size_t)p * DMODEL + d] + enc;
}

// ---------------- residual add + RMSNorm (also used for final norm) ----------------
__global__ __launch_bounds__(DMODEL)
void em_add_rmsnorm(const float* __restrict__ hidden, const float* __restrict__ res_in,
                    float* __restrict__ res_out, const float* __restrict__ w,
                    float* __restrict__ out) {
  const int tok = blockIdx.x;
  const int d = threadIdx.x;
  const size_t idx = (size_t)tok * DMODEL + d;
  const float v = hidden[idx] + res_in[idx];
  if (res_out) res_out[idx] = v;
  float ss = v * v;
  #pragma unroll
  for (int off = 32; off; off >>= 1) ss += __shfl_xor(ss, off, 64);
  __shared__ float red[6];
  if ((d & 63) == 0) red[d >> 6] = ss;
  __syncthreads();
  float tot = 0.f;
  #pragma unroll
  for (int i = 0; i < 6; ++i) tot += red[i];
  const float scale = rsqrtf(tot * (1.f / 384.f) + 1e-5f);
  out[idx] = v * scale * w[d];
}

// ---------------- C[M,N] = (A (+A2)) @ W^T, W is (N,K) row-major ----------------
// 64x64 tile, 4x4 per-thread register block, fp32. Requires N%64==0, K%16==0.
__global__ __launch_bounds__(256)
void em_gemm_nt(const float* __restrict__ A, const float* __restrict__ A2,
                const float* __restrict__ W, float* __restrict__ C,
                int M, int N, int K) {
  __shared__ float As[16][64];
  __shared__ float Bs[16][64];
  const int bm = blockIdx.y * 64;
  const int bn = blockIdx.x * 64;
  const int tid = threadIdx.x;
  const int tx = tid & 15, ty = tid >> 4;
  const int r = tid >> 2;
  const int kq = (tid & 3) * 4;
  float acc[4][4] = {{0.f, 0.f, 0.f, 0.f}, {0.f, 0.f, 0.f, 0.f},
                     {0.f, 0.f, 0.f, 0.f}, {0.f, 0.f, 0.f, 0.f}};
  for (int k0 = 0; k0 < K; k0 += 16) {
    float4 av = make_float4(0.f, 0.f, 0.f, 0.f);
    const int m = bm + r;
    if (m < M) {
      av = *reinterpret_cast<const float4*>(A + (size_t)m * K + k0 + kq);
      if (A2) {
        const float4 a2 = *reinterpret_cast<const float4*>(A2 + (size_t)m * K + k0 + kq);
        av.x += a2.x; av.y += a2.y; av.z += a2.z; av.w += a2.w;
      }
    }
    As[kq + 0][r] = av.x; As[kq + 1][r] = av.y; As[kq + 2][r] = av.z; As[kq + 3][r] = av.w;
    const float4 bv = *reinterpret_cast<const float4*>(W + (size_t)(bn + r) * K + k0 + kq);
    Bs[kq + 0][r] = bv.x; Bs[kq + 1][r] = bv.y; Bs[kq + 2][r] = bv.z; Bs[kq + 3][r] = bv.w;
    __syncthreads();
    #pragma unroll
    for (int k = 0; k < 16; ++k) {
      const float4 a = *reinterpret_cast<const float4*>(&As[k][ty * 4]);
      const float4 b = *reinterpret_cast<const float4*>(&Bs[k][tx * 4]);
      acc[0][0] += a.x * b.x; acc[0][1] += a.x * b.y; acc[0][2] += a.x * b.z; acc[0][3] += a.x * b.w;
      acc[1][0] += a.y * b.x; acc[1][1] += a.y * b.y; acc[1][2] += a.y * b.z; acc[1][3] += a.y * b.w;
      acc[2][0] += a.z * b.x; acc[2][1] += a.z * b.y; acc[2][2] += a.z * b.z; acc[2][3] += a.z * b.w;
      acc[3][0] += a.w * b.x; acc[3][1] += a.w * b.y; acc[3][2] += a.w * b.z; acc[3][3] += a.w * b.w;
    }
    __syncthreads();
  }
  #pragma unroll
  for (int i = 0; i < 4; ++i) {
    const int m = bm + ty * 4 + i;
    if (m < M) {
      *reinterpret_cast<float4*>(C + (size_t)m * N + bn + tx * 4) =
          make_float4(acc[i][0], acc[i][1], acc[i][2], acc[i][3]);
    }
  }
}

// ---------------- depthwise causal conv (fwd) / anti-causal (rev, pre-reversed coords) + SiLU ----------------
__global__ __launch_bounds__(256)
void em_conv_silu(const float* __restrict__ xz,
                  const float* __restrict__ cwf, const float* __restrict__ cbf,
                  const float* __restrict__ cwr, const float* __restrict__ cbr,
                  float* __restrict__ uf, float* __restrict__ ur, int L) {
  const int e = blockIdx.x * 256 + threadIdx.x;
  const int tok = blockIdx.y;
  const int dir = blockIdx.z;
  const int l = tok % L;
  const float* cw = dir ? cwr : cwf;
  const float* cb = dir ? cbr : cbf;
  const float w0 = cw[e * 4 + 0], w1 = cw[e * 4 + 1], w2 = cw[e * 4 + 2], w3 = cw[e * 4 + 3];
  float acc = cb[e];
  const float* base = xz + (size_t)tok * TWOE + e;
  if (dir == 0) {  // causal: sum_k u[l-3+k]*w[k]
    acc += base[0] * w3;
    if (l >= 1) acc += base[-(ptrdiff_t)TWOE] * w2;
    if (l >= 2) acc += base[-(ptrdiff_t)(2 * TWOE)] * w1;
    if (l >= 3) acc += base[-(ptrdiff_t)(3 * TWOE)] * w0;
  } else {         // reverse branch in original coords: sum_k u[l+3-k]*w[k]
    acc += base[0] * w3;
    if (l + 1 < L) acc += base[TWOE] * w2;
    if (l + 2 < L) acc += base[2 * TWOE] * w1;
    if (l + 3 < L) acc += base[3 * TWOE] * w0;
  }
  (dir ? ur : uf)[(size_t)tok * EDIM + e] = em_silu(acc);
}

// ---------------- xproj (56 dots of len 768) + dt proj (768 dots of len 24) + softplus ----------------
__global__ __launch_bounds__(256)
void em_xproj_dt(const float* __restrict__ uf, const float* __restrict__ ur,
                 const float* __restrict__ xpf, const float* __restrict__ xpr,
                 const float* __restrict__ dtwf, const float* __restrict__ dtwr,
                 const float* __restrict__ dtbf, const float* __restrict__ dtbr,
                 float* __restrict__ dblf, float* __restrict__ dblr,
                 float* __restrict__ dtf, float* __restrict__ dtr) {
  const int tok = blockIdx.x;
  const int dir = blockIdx.y;
  const float* u = (dir ? ur : uf) + (size_t)tok * EDIM;
  const float* xp = dir ? xpr : xpf;
  const float* dtw = dir ? dtwr : dtwf;
  const float* dtb = dir ? dtbr : dtbf;
  float* dblo = (dir ? dblr : dblf) + (size_t)tok * XDIM;
  float* dto = (dir ? dtr : dtf) + (size_t)tok * EDIM;
  __shared__ float us[EDIM];
  __shared__ float dbls[XDIM];
  const int tid = threadIdx.x;
  for (int i = tid; i < EDIM; i += 256) us[i] = u[i];
  __syncthreads();
  const int wv = tid >> 6, ln = tid & 63;
  for (int rr = 0; rr < 14; ++rr) {     // 4 waves x 14 rows = 56
    const int row = wv * 14 + rr;
    const float* xrow = xp + (size_t)row * EDIM;
    float p = 0.f;
    #pragma unroll
    for (int j = 0; j < EDIM / 64; ++j) p += us[ln + j * 64] * xrow[ln + j * 64];
    #pragma unroll
    for (int off = 32; off; off >>= 1) p += __shfl_xor(p, off, 64);
    if (ln == 0) dbls[row] = p;
  }
  __syncthreads();
  if (tid < XDIM) dblo[tid] = dbls[tid];
  for (int e = tid; e < EDIM; e += 256) {
    float a = dtb[e];
    const float* dw = dtw + (size_t)e * RDIM;
    #pragma unroll
    for (int rj = 0; rj < RDIM; ++rj) a += dbls[rj] * dw[rj];
    dto[e] = (a > 20.f) ? a : log1pf(__expf(a));   // softplus
  }
}

// ---------------- selective scan; dir=1 scans backward, writing at original positions ----------------
__global__ __launch_bounds__(256)
void em_scan(const float* __restrict__ dtf, const float* __restrict__ dtr,
             const float* __restrict__ uf, const float* __restrict__ ur,
             const float* __restrict__ dblf, const float* __restrict__ dblr,
             const float* __restrict__ xz,
             const float* __restrict__ Alogf, const float* __restrict__ Alogr,
             const float* __restrict__ Dpf, const float* __restrict__ Dpr,
             float* __restrict__ yf, float* __restrict__ yr, int L) {
  const int dir = blockIdx.z;
  const int n = blockIdx.y;
  const int tid = threadIdx.x;
  const int s = tid & 15;
  const int e = blockIdx.x * 16 + (tid >> 4);
  const float* dt = dir ? dtr : dtf;
  const float* u = dir ? ur : uf;
  const float* dbl = dir ? dblr : dblf;
  const float* Alog = dir ? Alogr : Alogf;
  const float* Dp = dir ? Dpr : Dpf;
  float* y = dir ? yr : yf;
  const float A = -__expf(Alog[e * SDIM + s]);
  const float De = Dp[e];
  float h = 0.f;
  for (int step = 0; step < L; ++step) {
    const int l = dir ? (L - 1 - step) : step;
    const size_t tok = (size_t)n * L + l;
    const float dtv = dt[tok * EDIM + e];
    const float uv = u[tok * EDIM + e];
    const float Bv = dbl[tok * XDIM + RDIM + s];
    const float Cv = dbl[tok * XDIM + RDIM + SDIM + s];
    h = __expf(dtv * A) * h + (dtv * uv) * Bv;
    float p = h * Cv;
    p += __shfl_xor(p, 1, 16);
    p += __shfl_xor(p, 2, 16);
    p += __shfl_xor(p, 4, 16);
    p += __shfl_xor(p, 8, 16);
    if (s == 0) {
      const float z = xz[tok * TWOE + EDIM + e];
      y[tok * EDIM + e] = (p + uv * De) * em_silu(z);
    }
  }
}

extern "C" void kernel_launch(void* const* d_in, const int* in_sizes, int n_in,
                              void* d_out, int out_size, void* d_ws, size_t ws_size,
                              hipStream_t stream) {
  const float* x         = (const float*)d_in[0];
  const float* patch_w   = (const float*)d_in[1];
  const float* patch_b   = (const float*)d_in[2];
  const float* cls_tok   = (const float*)d_in[3];
  const float* pos_emb   = (const float*)d_in[4];
  const float* normf     = (const float*)d_in[5];
  const float* sp_conv_w   = (const float*)d_in[6];
  const float* sp_conv_b   = (const float*)d_in[7];
  const float* sp_xproj    = (const float*)d_in[8];
  const float* sp_dtw      = (const float*)d_in[9];
  const float* sp_dtb      = (const float*)d_in[10];
  const float* sp_Alog     = (const float*)d_in[11];
  const float* sp_D        = (const float*)d_in[12];
  const float* sp_conv_w_r = (const float*)d_in[13];
  const float* sp_conv_b_r = (const float*)d_in[14];
  const float* sp_xproj_r  = (const float*)d_in[15];
  const float* sp_dtw_r    = (const float*)d_in[16];
  const float* sp_dtb_r    = (const float*)d_in[17];
  const float* sp_Alog_r   = (const float*)d_in[18];
  const float* sp_D_r      = (const float*)d_in[19];
  const float* tm_conv_w   = (const float*)d_in[20];
  const float* tm_conv_b   = (const float*)d_in[21];
  const float* tm_xproj    = (const float*)d_in[22];
  const float* tm_dtw      = (const float*)d_in[23];
  const float* tm_dtb      = (const float*)d_in[24];
  const float* tm_Alog     = (const float*)d_in[25];
  const float* tm_D        = (const float*)d_in[26];
  const float* sp_norm     = (const float*)d_in[27];
  const float* sp_inproj   = (const float*)d_in[28];
  const float* sp_outproj  = (const float*)d_in[29];
  const float* tm_norm     = (const float*)d_in[30];
  const float* tm_inproj   = (const float*)d_in[31];
  const float* tm_outproj  = (const float*)d_in[32];

  float* ws = (float*)d_ws;
  size_t o = 0;
  float* hidden   = ws + o; o += (size_t)NTOKS * DMODEL;
  float* residual = ws + o; o += (size_t)NTOKS * DMODEL;
  float* xn       = ws + o; o += (size_t)NTOKS * DMODEL;
  float* xz       = ws + o; o += (size_t)NTOKS * TWOE;
  float* u_f      = ws + o; o += (size_t)NTOKS * EDIM;
  float* u_r      = ws + o; o += (size_t)NTOKS * EDIM;
  float* dbl_f    = ws + o; o += (size_t)NTOKS * XDIM;
  float* dbl_r    = ws + o; o += (size_t)NTOKS * XDIM;
  float* dt_f     = ws + o; o += (size_t)NTOKS * EDIM;
  float* dt_r     = ws + o; o += (size_t)NTOKS * EDIM;
  float* y_f      = ws + o; o += (size_t)NTOKS * EDIM;
  float* y_r      = ws + o; o += (size_t)NTOKS * EDIM;

  hipMemsetAsync(residual, 0, (size_t)NTOKS * DMODEL * sizeof(float), stream);
  em_patch_embed<<<NTOKS, DMODEL, 0, stream>>>(x, patch_w, patch_b, cls_tok, pos_emb, hidden);

  // -------- 12 spatial bimamba blocks: N=16 sequences of L=197 --------
  for (int i = 0; i < NLAYER; ++i) {
    em_add_rmsnorm<<<NTOKS, DMODEL, 0, stream>>>(hidden, residual, residual,
                                                 sp_norm + (size_t)i * DMODEL, xn);
    em_gemm_nt<<<dim3(TWOE / 64, (NTOKS + 63) / 64), 256, 0, stream>>>(
        xn, nullptr, sp_inproj + (size_t)i * TWOE * DMODEL, xz, NTOKS, TWOE, DMODEL);
    em_conv_silu<<<dim3(EDIM / 256, NTOKS, 2), 256, 0, stream>>>(
        xz, sp_conv_w + (size_t)i * EDIM * 4, sp_conv_b + (size_t)i * EDIM,
        sp_conv_w_r + (size_t)i * EDIM * 4, sp_conv_b_r + (size_t)i * EDIM, u_f, u_r, 197);
    em_xproj_dt<<<dim3(NTOKS, 2), 256, 0, stream>>>(
        u_f, u_r, sp_xproj + (size_t)i * XDIM * EDIM, sp_xproj_r + (size_t)i * XDIM * EDIM,
        sp_dtw + (size_t)i * EDIM * RDIM, sp_dtw_r + (size_t)i * EDIM * RDIM,
        sp_dtb + (size_t)i * EDIM, sp_dtb_r + (size_t)i * EDIM, dbl_f, dbl_r, dt_f, dt_r);
    em_scan<<<dim3(EDIM / 16, 16, 2), 256, 0, stream>>>(
        dt_f, dt_r, u_f, u_r, dbl_f, dbl_r, xz,
        sp_Alog + (size_t)i * EDIM * SDIM, sp_Alog_r + (size_t)i * EDIM * SDIM,
        sp_D + (size_t)i * EDIM, sp_D_r + (size_t)i * EDIM, y_f, y_r, 197);
    em_gemm_nt<<<dim3(DMODEL / 64, (NTOKS + 63) / 64), 256, 0, stream>>>(
        y_f, y_r, sp_outproj + (size_t)i * DMODEL * EDIM, hidden, NTOKS, DMODEL, EDIM);
  }

  // -------- 12 temporal mamba blocks: N=2 sequences of L=1576 --------
  for (int i = 0; i < NLAYER; ++i) {
    em_add_rmsnorm<<<NTOKS, DMODEL, 0, stream>>>(hidden, residual, residual,
                                                 tm_norm + (size_t)i * DMODEL, xn);
    em_gemm_nt<<<dim3(TWOE / 64, (NTOKS + 63) / 64), 256, 0, stream>>>(
        xn, nullptr, tm_inproj + (size_t)i * TWOE * DMODEL, xz, NTOKS, TWOE, DMODEL);
    em_conv_silu<<<dim3(EDIM / 256, NTOKS, 1), 256, 0, stream>>>(
        xz, tm_conv_w + (size_t)i * EDIM * 4, tm_conv_b + (size_t)i * EDIM,
        tm_conv_w + (size_t)i * EDIM * 4, tm_conv_b + (size_t)i * EDIM, u_f, u_r, 1576);
    em_xproj_dt<<<dim3(NTOKS, 1), 256, 0, stream>>>(
        u_f, u_r, tm_xproj + (size_t)i * XDIM * EDIM, tm_xproj + (size_t)i * XDIM * EDIM,
        tm_dtw + (size_t)i * EDIM * RDIM, tm_dtw + (size_t)i * EDIM * RDIM,
        tm_dtb + (size_t)i * EDIM, tm_dtb + (size_t)i * EDIM, dbl_f, dbl_r, dt_f, dt_r);
    em_scan<<<dim3(EDIM / 16, 2, 1), 256, 0, stream>>>(
        dt_f, dt_r, u_f, u_r, dbl_f, dbl_r, xz,
        tm_Alog + (size_t)i * EDIM * SDIM, tm_Alog + (size_t)i * EDIM * SDIM,
        tm_D + (size_t)i * EDIM, tm_D + (size_t)i * EDIM, y_f, y_r, 1576);
    em_gemm_nt<<<dim3(DMODEL / 64, (NTOKS + 63) / 64), 256, 0, stream>>>(
        y_f, nullptr, tm_outproj + (size_t)i * DMODEL * EDIM, hidden, NTOKS, DMODEL, EDIM);
  }

  // -------- final: rmsnorm(hidden + residual) * normf -> d_out --------
  em_add_rmsnorm<<<NTOKS, DMODEL, 0, stream>>>(hidden, residual, nullptr, normf, (float*)d_out);
}

// Round 2
// 7045.404 us; speedup vs baseline: 3.0875x; 3.0875x over previous
//
#include <hip/hip_runtime.h>

#define NTOKS 3152      // B*T*P = 2*8*197
#define DMODEL 384
#define EDIM 768
#define TWOE 1536
#define SDIM 16
#define RDIM 24
#define XDIM 56         // R + 2S
#define NLAYER 12
#define CLEN 16         // scan chunk length

__device__ __forceinline__ float em_silu(float v) { return v / (1.f + __expf(-v)); }

// ---------------- patch embed + cls + pos embed + temporal sin/cos enc ----------------
__global__ __launch_bounds__(DMODEL)
void em_patch_embed(const float* __restrict__ x, const float* __restrict__ pw,
                    const float* __restrict__ pb, const float* __restrict__ cls,
                    const float* __restrict__ pos, float* __restrict__ hidden) {
  const int tok = blockIdx.x;          // (b*T+t)*P + p
  const int d = threadIdx.x;
  const int p = tok % 197;
  const int bt = tok / 197;
  const int t = bt % 8;
  const int b = bt / 8;
  if (p == 0) {
    hidden[(size_t)tok * DMODEL + d] = cls[d] + pos[d];
    return;
  }
  __shared__ float patch[768];         // 3 channels * 16*16 pixels
  const int np = p - 1;
  const int hp = np / 14, wp = np % 14;
  for (int i = d; i < 768; i += DMODEL) {
    const int c = i >> 8;
    const int rem = i & 255;
    const int ph = rem >> 4, pwx = rem & 15;
    patch[i] = x[(((size_t)(b * 3 + c) * 8 + t) * 224 + (hp * 16 + ph)) * 224 + (wp * 16 + pwx)];
  }
  __syncthreads();
  float acc = pb[d];
  const float* wrow = pw + (size_t)d * 768;
  #pragma unroll 8
  for (int k = 0; k < 768; ++k) acc += patch[k] * wrow[k];
  const float div = powf(10000.f, (float)(d & ~1) * (1.f / 384.f));
  const float ang = (float)t / div;
  const float enc = (d & 1) ? cosf(ang) : sinf(ang);
  hidden[(size_t)tok * DMODEL + d] = acc + pos[(size_t)p * DMODEL + d] + enc;
}

// ---------------- residual add + RMSNorm (also used for final norm) ----------------
__global__ __launch_bounds__(DMODEL)
void em_add_rmsnorm(const float* __restrict__ hidden, const float* __restrict__ res_in,
                    float* __restrict__ res_out, const float* __restrict__ w,
                    float* __restrict__ out) {
  const int tok = blockIdx.x;
  const int d = threadIdx.x;
  const size_t idx = (size_t)tok * DMODEL + d;
  const float v = hidden[idx] + res_in[idx];
  if (res_out) res_out[idx] = v;
  float ss = v * v;
  #pragma unroll
  for (int off = 32; off; off >>= 1) ss += __shfl_xor(ss, off, 64);
  __shared__ float red[6];
  if ((d & 63) == 0) red[d >> 6] = ss;
  __syncthreads();
  float tot = 0.f;
  #pragma unroll
  for (int i = 0; i < 6; ++i) tot += red[i];
  const float scale = rsqrtf(tot * (1.f / 384.f) + 1e-5f);
  out[idx] = v * scale * w[d];
}

// ---------------- C[M,N] = (A (+A2)) @ W^T, W is (N,K) row-major ----------------
__global__ __launch_bounds__(256)
void em_gemm_nt(const float* __restrict__ A, const float* __restrict__ A2,
                const float* __restrict__ W, float* __restrict__ C,
                int M, int N, int K) {
  __shared__ float As[16][64];
  __shared__ float Bs[16][64];
  const int bm = blockIdx.y * 64;
  const int bn = blockIdx.x * 64;
  const int tid = threadIdx.x;
  const int tx = tid & 15, ty = tid >> 4;
  const int r = tid >> 2;
  const int kq = (tid & 3) * 4;
  float acc[4][4] = {{0.f, 0.f, 0.f, 0.f}, {0.f, 0.f, 0.f, 0.f},
                     {0.f, 0.f, 0.f, 0.f}, {0.f, 0.f, 0.f, 0.f}};
  for (int k0 = 0; k0 < K; k0 += 16) {
    float4 av = make_float4(0.f, 0.f, 0.f, 0.f);
    const int m = bm + r;
    if (m < M) {
      av = *reinterpret_cast<const float4*>(A + (size_t)m * K + k0 + kq);
      if (A2) {
        const float4 a2 = *reinterpret_cast<const float4*>(A2 + (size_t)m * K + k0 + kq);
        av.x += a2.x; av.y += a2.y; av.z += a2.z; av.w += a2.w;
      }
    }
    As[kq + 0][r] = av.x; As[kq + 1][r] = av.y; As[kq + 2][r] = av.z; As[kq + 3][r] = av.w;
    const float4 bv = *reinterpret_cast<const float4*>(W + (size_t)(bn + r) * K + k0 + kq);
    Bs[kq + 0][r] = bv.x; Bs[kq + 1][r] = bv.y; Bs[kq + 2][r] = bv.z; Bs[kq + 3][r] = bv.w;
    __syncthreads();
    #pragma unroll
    for (int k = 0; k < 16; ++k) {
      const float4 a = *reinterpret_cast<const float4*>(&As[k][ty * 4]);
      const float4 b = *reinterpret_cast<const float4*>(&Bs[k][tx * 4]);
      acc[0][0] += a.x * b.x; acc[0][1] += a.x * b.y; acc[0][2] += a.x * b.z; acc[0][3] += a.x * b.w;
      acc[1][0] += a.y * b.x; acc[1][1] += a.y * b.y; acc[1][2] += a.y * b.z; acc[1][3] += a.y * b.w;
      acc[2][0] += a.z * b.x; acc[2][1] += a.z * b.y; acc[2][2] += a.z * b.z; acc[2][3] += a.z * b.w;
      acc[3][0] += a.w * b.x; acc[3][1] += a.w * b.y; acc[3][2] += a.w * b.z; acc[3][3] += a.w * b.w;
    }
    __syncthreads();
  }
  #pragma unroll
  for (int i = 0; i < 4; ++i) {
    const int m = bm + ty * 4 + i;
    if (m < M) {
      *reinterpret_cast<float4*>(C + (size_t)m * N + bn + tx * 4) =
          make_float4(acc[i][0], acc[i][1], acc[i][2], acc[i][3]);
    }
  }
}

// ---------------- depthwise causal conv (fwd) / anti-causal (rev) + SiLU ----------------
__global__ __launch_bounds__(256)
void em_conv_silu(const float* __restrict__ xz,
                  const float* __restrict__ cwf, const float* __restrict__ cbf,
                  const float* __restrict__ cwr, const float* __restrict__ cbr,
                  float* __restrict__ uf, float* __restrict__ ur, int L) {
  const int e = blockIdx.x * 256 + threadIdx.x;
  const int tok = blockIdx.y;
  const int dir = blockIdx.z;
  const int l = tok % L;
  const float* cw = dir ? cwr : cwf;
  const float* cb = dir ? cbr : cbf;
  const float w0 = cw[e * 4 + 0], w1 = cw[e * 4 + 1], w2 = cw[e * 4 + 2], w3 = cw[e * 4 + 3];
  float acc = cb[e];
  const float* base = xz + (size_t)tok * TWOE + e;
  if (dir == 0) {
    acc += base[0] * w3;
    if (l >= 1) acc += base[-(ptrdiff_t)TWOE] * w2;
    if (l >= 2) acc += base[-(ptrdiff_t)(2 * TWOE)] * w1;
    if (l >= 3) acc += base[-(ptrdiff_t)(3 * TWOE)] * w0;
  } else {
    acc += base[0] * w3;
    if (l + 1 < L) acc += base[TWOE] * w2;
    if (l + 2 < L) acc += base[2 * TWOE] * w1;
    if (l + 3 < L) acc += base[3 * TWOE] * w0;
  }
  (dir ? ur : uf)[(size_t)tok * EDIM + e] = em_silu(acc);
}

// ---------------- xproj (56 dots of len 768) + dt proj + softplus ----------------
__global__ __launch_bounds__(256)
void em_xproj_dt(const float* __restrict__ uf, const float* __restrict__ ur,
                 const float* __restrict__ xpf, const float* __restrict__ xpr,
                 const float* __restrict__ dtwf, const float* __restrict__ dtwr,
                 const float* __restrict__ dtbf, const float* __restrict__ dtbr,
                 float* __restrict__ dblf, float* __restrict__ dblr,
                 float* __restrict__ dtf, float* __restrict__ dtr) {
  const int tok = blockIdx.x;
  const int dir = blockIdx.y;
  const float* u = (dir ? ur : uf) + (size_t)tok * EDIM;
  const float* xp = dir ? xpr : xpf;
  const float* dtw = dir ? dtwr : dtwf;
  const float* dtb = dir ? dtbr : dtbf;
  float* dblo = (dir ? dblr : dblf) + (size_t)tok * XDIM;
  float* dto = (dir ? dtr : dtf) + (size_t)tok * EDIM;
  __shared__ float us[EDIM];
  __shared__ float dbls[XDIM];
  const int tid = threadIdx.x;
  for (int i = tid; i < EDIM; i += 256) us[i] = u[i];
  __syncthreads();
  const int wv = tid >> 6, ln = tid & 63;
  for (int rr = 0; rr < 14; ++rr) {     // 4 waves x 14 rows = 56
    const int row = wv * 14 + rr;
    const float* xrow = xp + (size_t)row * EDIM;
    float p = 0.f;
    #pragma unroll
    for (int j = 0; j < EDIM / 64; ++j) p += us[ln + j * 64] * xrow[ln + j * 64];
    #pragma unroll
    for (int off = 32; off; off >>= 1) p += __shfl_xor(p, off, 64);
    if (ln == 0) dbls[row] = p;
  }
  __syncthreads();
  if (tid < XDIM) dblo[tid] = dbls[tid];
  for (int e = tid; e < EDIM; e += 256) {
    float a = dtb[e];
    const float* dw = dtw + (size_t)e * RDIM;
    #pragma unroll
    for (int rj = 0; rj < RDIM; ++rj) a += dbls[rj] * dw[rj];
    dto[e] = (a > 20.f) ? a : log1pf(__expf(a));   // softplus
  }
}

// ================= chunked parallel selective scan =================
// pos = step index along scan direction; l = dir ? L-1-pos : pos.
// Chunk c covers pos in [c*CLEN, c*CLEN+len). Thread = one e, 16 s-states in regs.

// pass 1: per-chunk summary with h_in = 0 -> P (prod of a), Hsum (final state)
// grid: x = EDIM/256, y = n*nchunks, z = dirs
__global__ __launch_bounds__(256)
void em_scan_sum(const float* __restrict__ dtf, const float* __restrict__ dtr,
                 const float* __restrict__ uf, const float* __restrict__ ur,
                 const float* __restrict__ dblf, const float* __restrict__ dblr,
                 const float* __restrict__ Alogf, const float* __restrict__ Alogr,
                 float* __restrict__ Pfw, float* __restrict__ Prv,
                 float* __restrict__ Hfw, float* __restrict__ Hrv,
                 int L, int nchunks) {
  const int dir = blockIdx.z;
  const int n = blockIdx.y / nchunks;
  const int c = blockIdx.y % nchunks;
  const int tid = threadIdx.x;
  const int e = blockIdx.x * 256 + tid;
  const float* dt = dir ? dtr : dtf;
  const float* u = dir ? ur : uf;
  const float* dbl = dir ? dblr : dblf;
  const float* Alog = dir ? Alogr : Alogf;
  float* P = dir ? Prv : Pfw;
  float* H = dir ? Hrv : Hfw;
  const int p0 = c * CLEN;
  const int len = min(CLEN, L - p0);
  __shared__ float Bs[CLEN][SDIM];
  {
    const int j = tid >> 4, s = tid & 15;      // 256 = CLEN*16
    if (j < len) {
      const int pos = p0 + j;
      const int l = dir ? (L - 1 - pos) : pos;
      Bs[j][s] = dbl[((size_t)n * L + l) * XDIM + RDIM + s];
    }
  }
  __syncthreads();
  float A[SDIM], h[SDIM], Pp[SDIM];
  #pragma unroll
  for (int s = 0; s < SDIM; ++s) {
    A[s] = -__expf(Alog[e * SDIM + s]);
    h[s] = 0.f; Pp[s] = 1.f;
  }
  for (int j = 0; j < len; ++j) {
    const int pos = p0 + j;
    const int l = dir ? (L - 1 - pos) : pos;
    const size_t tok = (size_t)n * L + l;
    const float dtv = dt[tok * EDIM + e];
    const float dtu = dtv * u[tok * EDIM + e];
    #pragma unroll
    for (int s = 0; s < SDIM; ++s) {
      const float a = __expf(dtv * A[s]);
      h[s] = a * h[s] + dtu * Bs[j][s];
      Pp[s] *= a;
    }
  }
  const size_t base = ((size_t)(n * nchunks + c) * EDIM + e) * SDIM;
  #pragma unroll
  for (int s = 0; s < SDIM; ++s) { P[base + s] = Pp[s]; H[base + s] = h[s]; }
}

// pass 2: sequential combine over chunks; overwrites H in-place with H_in per chunk.
// grid: x = n*EDIM*SDIM/256, z = dirs
__global__ __launch_bounds__(256)
void em_scan_combine(const float* __restrict__ Pfw, const float* __restrict__ Prv,
                     float* __restrict__ Hfw, float* __restrict__ Hrv, int nchunks) {
  const int dir = blockIdx.z;
  const int idx = blockIdx.x * 256 + threadIdx.x;   // n*(E*S) + e*S + s
  const int n = idx / (EDIM * SDIM);
  const int r = idx % (EDIM * SDIM);
  const float* P = dir ? Prv : Pfw;
  float* H = dir ? Hrv : Hfw;
  float h = 0.f;
  for (int c = 0; c < nchunks; ++c) {
    const size_t b = (size_t)(n * nchunks + c) * (EDIM * SDIM) + r;
    const float pv = P[b];
    const float hf = H[b];
    H[b] = h;                 // H now holds the chunk's incoming state
    h = pv * h + hf;
  }
}

// pass 3: full scan per chunk from H_in, write gated y at original positions.
// grid: x = EDIM/256, y = n*nchunks, z = dirs
__global__ __launch_bounds__(256)
void em_scan_out(const float* __restrict__ dtf, const float* __restrict__ dtr,
                 const float* __restrict__ uf, const float* __restrict__ ur,
                 const float* __restrict__ dblf, const float* __restrict__ dblr,
                 const float* __restrict__ xz,
                 const float* __restrict__ Alogf, const float* __restrict__ Alogr,
                 const float* __restrict__ Dpf, const float* __restrict__ Dpr,
                 const float* __restrict__ Hfw, const float* __restrict__ Hrv,
                 float* __restrict__ yf, float* __restrict__ yr,
                 int L, int nchunks) {
  const int dir = blockIdx.z;
  const int n = blockIdx.y / nchunks;
  const int c = blockIdx.y % nchunks;
  const int tid = threadIdx.x;
  const int e = blockIdx.x * 256 + tid;
  const float* dt = dir ? dtr : dtf;
  const float* u = dir ? ur : uf;
  const float* dbl = dir ? dblr : dblf;
  const float* Alog = dir ? Alogr : Alogf;
  const float* Dp = dir ? Dpr : Dpf;
  const float* Hin = dir ? Hrv : Hfw;
  float* y = dir ? yr : yf;
  const int p0 = c * CLEN;
  const int len = min(CLEN, L - p0);
  __shared__ float Bs[CLEN][SDIM];
  __shared__ float Cs[CLEN][SDIM];
  for (int i = tid; i < 32 * CLEN; i += 256) {
    const int j = i >> 5, v = i & 31;
    if (j < len) {
      const int pos = p0 + j;
      const int l = dir ? (L - 1 - pos) : pos;
      const float val = dbl[((size_t)n * L + l) * XDIM + RDIM + v];
      if (v < 16) Bs[j][v] = val; else Cs[j][v - 16] = val;
    }
  }
  __syncthreads();
  float A[SDIM], h[SDIM];
  const size_t base = ((size_t)(n * nchunks + c) * EDIM + e) * SDIM;
  #pragma unroll
  for (int s = 0; s < SDIM; ++s) {
    A[s] = -__expf(Alog[e * SDIM + s]);
    h[s] = Hin[base + s];
  }
  const float De = Dp[e];
  for (int j = 0; j < len; ++j) {
    const int pos = p0 + j;
    const int l = dir ? (L - 1 - pos) : pos;
    const size_t tok = (size_t)n * L + l;
    const float dtv = dt[tok * EDIM + e];
    const float uv = u[tok * EDIM + e];
    const float dtu = dtv * uv;
    float acc = 0.f;
    #pragma unroll
    for (int s = 0; s < SDIM; ++s) {
      const float a = __expf(dtv * A[s]);
      h[s] = a * h[s] + dtu * Bs[j][s];
      acc += h[s] * Cs[j][s];
    }
    const float z = xz[tok * TWOE + EDIM + e];
    y[tok * EDIM + e] = (acc + uv * De) * em_silu(z);
  }
}

extern "C" void kernel_launch(void* const* d_in, const int* in_sizes, int n_in,
                              void* d_out, int out_size, void* d_ws, size_t ws_size,
                              hipStream_t stream) {
  const float* x         = (const float*)d_in[0];
  const float* patch_w   = (const float*)d_in[1];
  const float* patch_b   = (const float*)d_in[2];
  const float* cls_tok   = (const float*)d_in[3];
  const float* pos_emb   = (const float*)d_in[4];
  const float* normf     = (const float*)d_in[5];
  const float* sp_conv_w   = (const float*)d_in[6];
  const float* sp_conv_b   = (const float*)d_in[7];
  const float* sp_xproj    = (const float*)d_in[8];
  const float* sp_dtw      = (const float*)d_in[9];
  const float* sp_dtb      = (const float*)d_in[10];
  const float* sp_Alog     = (const float*)d_in[11];
  const float* sp_D        = (const float*)d_in[12];
  const float* sp_conv_w_r = (const float*)d_in[13];
  const float* sp_conv_b_r = (const float*)d_in[14];
  const float* sp_xproj_r  = (const float*)d_in[15];
  const float* sp_dtw_r    = (const float*)d_in[16];
  const float* sp_dtb_r    = (const float*)d_in[17];
  const float* sp_Alog_r   = (const float*)d_in[18];
  const float* sp_D_r      = (const float*)d_in[19];
  const float* tm_conv_w   = (const float*)d_in[20];
  const float* tm_conv_b   = (const float*)d_in[21];
  const float* tm_xproj    = (const float*)d_in[22];
  const float* tm_dtw      = (const float*)d_in[23];
  const float* tm_dtb      = (const float*)d_in[24];
  const float* tm_Alog     = (const float*)d_in[25];
  const float* tm_D        = (const float*)d_in[26];
  const float* sp_norm     = (const float*)d_in[27];
  const float* sp_inproj   = (const float*)d_in[28];
  const float* sp_outproj  = (const float*)d_in[29];
  const float* tm_norm     = (const float*)d_in[30];
  const float* tm_inproj   = (const float*)d_in[31];
  const float* tm_outproj  = (const float*)d_in[32];

  float* ws = (float*)d_ws;
  size_t o = 0;
  float* hidden   = ws + o; o += (size_t)NTOKS * DMODEL;
  float* residual = ws + o; o += (size_t)NTOKS * DMODEL;
  float* xn       = ws + o; o += (size_t)NTOKS * DMODEL;
  float* xz       = ws + o; o += (size_t)NTOKS * TWOE;
  float* u_f      = ws + o; o += (size_t)NTOKS * EDIM;
  float* u_r      = ws + o; o += (size_t)NTOKS * EDIM;
  float* dbl_f    = ws + o; o += (size_t)NTOKS * XDIM;
  float* dbl_r    = ws + o; o += (size_t)NTOKS * XDIM;
  float* dt_f     = ws + o; o += (size_t)NTOKS * EDIM;
  float* dt_r     = ws + o; o += (size_t)NTOKS * EDIM;
  float* y_f      = ws + o; o += (size_t)NTOKS * EDIM;
  float* y_r      = ws + o; o += (size_t)NTOKS * EDIM;
  // scan chunk summaries: max(n*nchunks) = max(2*99, 16*13) = 208 chunk-sets
  const size_t sum_elems = (size_t)208 * EDIM * SDIM;
  float* scanP_f  = ws + o; o += sum_elems;
  float* scanP_r  = ws + o; o += sum_elems;
  float* scanH_f  = ws + o; o += sum_elems;
  float* scanH_r  = ws + o; o += sum_elems;

  const int L_sp = 197, NC_sp = (L_sp + CLEN - 1) / CLEN;   // 13
  const int L_tm = 1576, NC_tm = (L_tm + CLEN - 1) / CLEN;  // 99

  hipMemsetAsync(residual, 0, (size_t)NTOKS * DMODEL * sizeof(float), stream);
  em_patch_embed<<<NTOKS, DMODEL, 0, stream>>>(x, patch_w, patch_b, cls_tok, pos_emb, hidden);

  // -------- 12 spatial bimamba blocks: N=16 sequences of L=197 --------
  for (int i = 0; i < NLAYER; ++i) {
    em_add_rmsnorm<<<NTOKS, DMODEL, 0, stream>>>(hidden, residual, residual,
                                                 sp_norm + (size_t)i * DMODEL, xn);
    em_gemm_nt<<<dim3(TWOE / 64, (NTOKS + 63) / 64), 256, 0, stream>>>(
        xn, nullptr, sp_inproj + (size_t)i * TWOE * DMODEL, xz, NTOKS, TWOE, DMODEL);
    em_conv_silu<<<dim3(EDIM / 256, NTOKS, 2), 256, 0, stream>>>(
        xz, sp_conv_w + (size_t)i * EDIM * 4, sp_conv_b + (size_t)i * EDIM,
        sp_conv_w_r + (size_t)i * EDIM * 4, sp_conv_b_r + (size_t)i * EDIM, u_f, u_r, L_sp);
    em_xproj_dt<<<dim3(NTOKS, 2), 256, 0, stream>>>(
        u_f, u_r, sp_xproj + (size_t)i * XDIM * EDIM, sp_xproj_r + (size_t)i * XDIM * EDIM,
        sp_dtw + (size_t)i * EDIM * RDIM, sp_dtw_r + (size_t)i * EDIM * RDIM,
        sp_dtb + (size_t)i * EDIM, sp_dtb_r + (size_t)i * EDIM, dbl_f, dbl_r, dt_f, dt_r);
    em_scan_sum<<<dim3(EDIM / 256, 16 * NC_sp, 2), 256, 0, stream>>>(
        dt_f, dt_r, u_f, u_r, dbl_f, dbl_r,
        sp_Alog + (size_t)i * EDIM * SDIM, sp_Alog_r + (size_t)i * EDIM * SDIM,
        scanP_f, scanP_r, scanH_f, scanH_r, L_sp, NC_sp);
    em_scan_combine<<<dim3(16 * EDIM * SDIM / 256, 1, 2), 256, 0, stream>>>(
        scanP_f, scanP_r, scanH_f, scanH_r, NC_sp);
    em_scan_out<<<dim3(EDIM / 256, 16 * NC_sp, 2), 256, 0, stream>>>(
        dt_f, dt_r, u_f, u_r, dbl_f, dbl_r, xz,
        sp_Alog + (size_t)i * EDIM * SDIM, sp_Alog_r + (size_t)i * EDIM * SDIM,
        sp_D + (size_t)i * EDIM, sp_D_r + (size_t)i * EDIM,
        scanH_f, scanH_r, y_f, y_r, L_sp, NC_sp);
    em_gemm_nt<<<dim3(DMODEL / 64, (NTOKS + 63) / 64), 256, 0, stream>>>(
        y_f, y_r, sp_outproj + (size_t)i * DMODEL * EDIM, hidden, NTOKS, DMODEL, EDIM);
  }

  // -------- 12 temporal mamba blocks: N=2 sequences of L=1576 --------
  for (int i = 0; i < NLAYER; ++i) {
    em_add_rmsnorm<<<NTOKS, DMODEL, 0, stream>>>(hidden, residual, residual,
                                                 tm_norm + (size_t)i * DMODEL, xn);
    em_gemm_nt<<<dim3(TWOE / 64, (NTOKS + 63) / 64), 256, 0, stream>>>(
        xn, nullptr, tm_inproj + (size_t)i * TWOE * DMODEL, xz, NTOKS, TWOE, DMODEL);
    em_conv_silu<<<dim3(EDIM / 256, NTOKS, 1), 256, 0, stream>>>(
        xz, tm_conv_w + (size_t)i * EDIM * 4, tm_conv_b + (size_t)i * EDIM,
        tm_conv_w + (size_t)i * EDIM * 4, tm_conv_b + (size_t)i * EDIM, u_f, u_r, L_tm);
    em_xproj_dt<<<dim3(NTOKS, 1), 256, 0, stream>>>(
        u_f, u_r, tm_xproj + (size_t)i * XDIM * EDIM, tm_xproj + (size_t)i * XDIM * EDIM,
        tm_dtw + (size_t)i * EDIM * RDIM, tm_dtw + (size_t)i * EDIM * RDIM,
        tm_dtb + (size_t)i * EDIM, tm_dtb + (size_t)i * EDIM, dbl_f, dbl_r, dt_f, dt_r);
    em_scan_sum<<<dim3(EDIM / 256, 2 * NC_tm, 1), 256, 0, stream>>>(
        dt_f, dt_r, u_f, u_r, dbl_f, dbl_r,
        tm_Alog + (size_t)i * EDIM * SDIM, tm_Alog + (size_t)i * EDIM * SDIM,
        scanP_f, scanP_r, scanH_f, scanH_r, L_tm, NC_tm);
    em_scan_combine<<<dim3(2 * EDIM * SDIM / 256, 1, 1), 256, 0, stream>>>(
        scanP_f, scanP_r, scanH_f, scanH_r, NC_tm);
    em_scan_out<<<dim3(EDIM / 256, 2 * NC_tm, 1), 256, 0, stream>>>(
        dt_f, dt_r, u_f, u_r, dbl_f, dbl_r, xz,
        tm_Alog + (size_t)i * EDIM * SDIM, tm_Alog + (size_t)i * EDIM * SDIM,
        tm_D + (size_t)i * EDIM, tm_D + (size_t)i * EDIM,
        scanH_f, scanH_r, y_f, y_r, L_tm, NC_tm);
    em_gemm_nt<<<dim3(DMODEL / 64, (NTOKS + 63) / 64), 256, 0, stream>>>(
        y_f, nullptr, tm_outproj + (size_t)i * DMODEL * EDIM, hidden, NTOKS, DMODEL, EDIM);
  }

  // -------- final: rmsnorm(hidden + residual) * normf -> d_out --------
  em_add_rmsnorm<<<NTOKS, DMODEL, 0, stream>>>(hidden, residual, nullptr, normf, (float*)d_out);
}

// Round 3
// 4750.896 us; speedup vs baseline: 4.5787x; 1.4830x over previous
//
#include <hip/hip_runtime.h>

#define NTOKS 3152      // B*T*P = 2*8*197
#define DMODEL 384
#define EDIM 768
#define TWOE 1536
#define SDIM 16
#define RDIM 24
#define XDIM 56         // R + 2S
#define NLAYER 12
#define CLEN 16         // scan chunk length
#define NPATCH 3136     // 16 * 196

typedef __attribute__((ext_vector_type(8))) short bf16x8;
typedef __attribute__((ext_vector_type(4))) float f32x4;

__device__ __forceinline__ float em_silu(float v) { return v / (1.f + __expf(-v)); }

__device__ __forceinline__ unsigned short f2bf(float f) {
  union { float f; unsigned int u; } v; v.f = f;
  const unsigned int r = v.u + 0x7fffu + ((v.u >> 16) & 1u);   // RTNE
  return (unsigned short)(r >> 16);
}
__device__ __forceinline__ unsigned int f2bf2(float lo, float hi) {
  return (unsigned int)f2bf(lo) | ((unsigned int)f2bf(hi) << 16);
}

// ---------------- im2col for patch embed: col[3136][768] ----------------
__global__ __launch_bounds__(256)
void em_im2col(const float* __restrict__ x, float* __restrict__ col) {
  const int g = blockIdx.x * 256 + threadIdx.x;   // pr*768 + cc
  const int pr = g / 768;
  const int cc = g - pr * 768;
  const int np = pr % 196;
  const int bt = pr / 196;
  const int t = bt & 7, b = bt >> 3;
  const int hp = np / 14, wp = np - hp * 14;
  const int c = cc >> 8;
  const int rem = cc & 255;
  const int ph = rem >> 4, pw = rem & 15;
  col[g] = x[(((size_t)(b * 3 + c) * 8 + t) * 224 + (hp * 16 + ph)) * 224 + (wp * 16 + pw)];
}

// ---------------- patch embed epilogue: bias + pos + cls + temporal enc ----------------
__global__ __launch_bounds__(DMODEL)
void em_embed_final(const float* __restrict__ tmpP, const float* __restrict__ pb,
                    const float* __restrict__ cls, const float* __restrict__ pos,
                    float* __restrict__ hidden) {
  const int tok = blockIdx.x;
  const int d = threadIdx.x;
  const int p = tok % 197;
  const int bt = tok / 197;
  const int t = bt & 7;
  if (p == 0) {
    hidden[(size_t)tok * DMODEL + d] = cls[d] + pos[d];
    return;
  }
  const int np = p - 1;
  const float div = powf(10000.f, (float)(d & ~1) * (1.f / 384.f));
  const float ang = (float)t / div;
  const float enc = (d & 1) ? cosf(ang) : sinf(ang);
  hidden[(size_t)tok * DMODEL + d] =
      tmpP[((size_t)bt * 196 + np) * DMODEL + d] + pb[d] + pos[(size_t)p * DMODEL + d] + enc;
}

// ---------------- residual add + RMSNorm (also used for final norm) ----------------
__global__ __launch_bounds__(DMODEL)
void em_add_rmsnorm(const float* __restrict__ hidden, const float* __restrict__ res_in,
                    float* __restrict__ res_out, const float* __restrict__ w,
                    float* __restrict__ out) {
  const int tok = blockIdx.x;
  const int d = threadIdx.x;
  const size_t idx = (size_t)tok * DMODEL + d;
  const float v = hidden[idx] + res_in[idx];
  if (res_out) res_out[idx] = v;
  float ss = v * v;
  #pragma unroll
  for (int off = 32; off; off >>= 1) ss += __shfl_xor(ss, off, 64);
  __shared__ float red[6];
  if ((d & 63) == 0) red[d >> 6] = ss;
  __syncthreads();
  float tot = 0.f;
  #pragma unroll
  for (int i = 0; i < 6; ++i) tot += red[i];
  const float scale = rsqrtf(tot * (1.f / 384.f) + 1e-5f);
  out[idx] = v * scale * w[d];
}

// ================ bf16 MFMA GEMM: C[M,N] = (A (+A2))[M,K] @ W[N,K]^T ================
// fp32 in/out, bf16 MFMA compute, fp32 accumulate. Requires N%64==0, K%32==0.
// Block 256 thr = 4 waves (2x2), tile 128M x 64N, BK=32; wave computes 64x32.
#define TM 128
#define TN 64
#define LDT 40   // ushorts per LDS row (32 + 8 pad) -> 80 B, keeps 16B alignment
__global__ __launch_bounds__(256)
void em_gemm_bf16(const float* __restrict__ A, const float* __restrict__ A2,
                  const float* __restrict__ W, float* __restrict__ C,
                  int M, int N, int K) {
  __shared__ unsigned short As[TM * LDT];   // 10240 B
  __shared__ unsigned short Bs[TN * LDT];   // 5120 B
  const int tid = threadIdx.x;
  const int bm = blockIdx.y * TM;
  const int bn = blockIdx.x * TN;
  const int wave = tid >> 6, lane = tid & 63;
  const int wm = (wave >> 1) * 64, wn = (wave & 1) * 32;
  const int mq = lane & 15, quad = lane >> 4;
  f32x4 acc[4][2] = {};
  const int ar = tid >> 1;            // A staging: row 0..127
  const int ak = (tid & 1) * 16;      // k offset 0/16 (16 floats per thread)
  const int br = tid >> 2;            // B staging: row 0..63
  const int bk = (tid & 3) * 8;       // 8 floats per thread

  for (int kk = 0; kk < K; kk += 32) {
    // ---- stage A (128x32) fp32 -> bf16 ----
    {
      float vals[16];
      const int row = bm + ar;
      if (row < M) {
        const float* p = A + (size_t)row * K + kk + ak;
        #pragma unroll
        for (int q = 0; q < 4; ++q) {
          const float4 v = *reinterpret_cast<const float4*>(p + q * 4);
          vals[q * 4 + 0] = v.x; vals[q * 4 + 1] = v.y;
          vals[q * 4 + 2] = v.z; vals[q * 4 + 3] = v.w;
        }
        if (A2) {
          const float* p2 = A2 + (size_t)row * K + kk + ak;
          #pragma unroll
          for (int q = 0; q < 4; ++q) {
            const float4 v = *reinterpret_cast<const float4*>(p2 + q * 4);
            vals[q * 4 + 0] += v.x; vals[q * 4 + 1] += v.y;
            vals[q * 4 + 2] += v.z; vals[q * 4 + 3] += v.w;
          }
        }
      } else {
        #pragma unroll
        for (int q = 0; q < 16; ++q) vals[q] = 0.f;
      }
      uint4 pk0, pk1;
      pk0.x = f2bf2(vals[0], vals[1]);  pk0.y = f2bf2(vals[2], vals[3]);
      pk0.z = f2bf2(vals[4], vals[5]);  pk0.w = f2bf2(vals[6], vals[7]);
      pk1.x = f2bf2(vals[8], vals[9]);  pk1.y = f2bf2(vals[10], vals[11]);
      pk1.z = f2bf2(vals[12], vals[13]); pk1.w = f2bf2(vals[14], vals[15]);
      uint4* dst = reinterpret_cast<uint4*>(As + ar * LDT + ak);
      dst[0] = pk0; dst[1] = pk1;
    }
    // ---- stage B (64x32) fp32 -> bf16 ----
    {
      const float* p = W + (size_t)(bn + br) * K + kk + bk;
      const float4 v0 = *reinterpret_cast<const float4*>(p);
      const float4 v1 = *reinterpret_cast<const float4*>(p + 4);
      uint4 pk;
      pk.x = f2bf2(v0.x, v0.y); pk.y = f2bf2(v0.z, v0.w);
      pk.z = f2bf2(v1.x, v1.y); pk.w = f2bf2(v1.z, v1.w);
      *reinterpret_cast<uint4*>(Bs + br * LDT + bk) = pk;
    }
    __syncthreads();
    // ---- fragments + MFMA ----
    bf16x8 bfr[2];
    #pragma unroll
    for (int j = 0; j < 2; ++j)
      bfr[j] = *reinterpret_cast<const bf16x8*>(Bs + (wn + j * 16 + mq) * LDT + quad * 8);
    #pragma unroll
    for (int i = 0; i < 4; ++i) {
      const bf16x8 afr = *reinterpret_cast<const bf16x8*>(As + (wm + i * 16 + mq) * LDT + quad * 8);
      acc[i][0] = __builtin_amdgcn_mfma_f32_16x16x32_bf16(afr, bfr[0], acc[i][0], 0, 0, 0);
      acc[i][1] = __builtin_amdgcn_mfma_f32_16x16x32_bf16(afr, bfr[1], acc[i][1], 0, 0, 0);
    }
    __syncthreads();
  }
  // ---- epilogue: C/D layout col=lane&15, row=quad*4+reg ----
  #pragma unroll
  for (int i = 0; i < 4; ++i) {
    const int mbase = bm + wm + i * 16 + quad * 4;
    #pragma unroll
    for (int j = 0; j < 2; ++j) {
      const int col = bn + wn + j * 16 + mq;
      #pragma unroll
      for (int p = 0; p < 4; ++p) {
        const int m = mbase + p;
        if (m < M) C[(size_t)m * N + col] = acc[i][j][p];
      }
    }
  }
}

// ---------------- depthwise causal conv (fwd) / anti-causal (rev) + SiLU ----------------
__global__ __launch_bounds__(256)
void em_conv_silu(const float* __restrict__ xz,
                  const float* __restrict__ cwf, const float* __restrict__ cbf,
                  const float* __restrict__ cwr, const float* __restrict__ cbr,
                  float* __restrict__ uf, float* __restrict__ ur, int L) {
  const int e = blockIdx.x * 256 + threadIdx.x;
  const int tok = blockIdx.y;
  const int dir = blockIdx.z;
  const int l = tok % L;
  const float* cw = dir ? cwr : cwf;
  const float* cb = dir ? cbr : cbf;
  const float w0 = cw[e * 4 + 0], w1 = cw[e * 4 + 1], w2 = cw[e * 4 + 2], w3 = cw[e * 4 + 3];
  float acc = cb[e];
  const float* base = xz + (size_t)tok * TWOE + e;
  if (dir == 0) {
    acc += base[0] * w3;
    if (l >= 1) acc += base[-(ptrdiff_t)TWOE] * w2;
    if (l >= 2) acc += base[-(ptrdiff_t)(2 * TWOE)] * w1;
    if (l >= 3) acc += base[-(ptrdiff_t)(3 * TWOE)] * w0;
  } else {
    acc += base[0] * w3;
    if (l + 1 < L) acc += base[TWOE] * w2;
    if (l + 2 < L) acc += base[2 * TWOE] * w1;
    if (l + 3 < L) acc += base[3 * TWOE] * w0;
  }
  (dir ? ur : uf)[(size_t)tok * EDIM + e] = em_silu(acc);
}

// ---------------- xproj (56 dots of len 768) + dt proj + softplus ----------------
__global__ __launch_bounds__(256)
void em_xproj_dt(const float* __restrict__ uf, const float* __restrict__ ur,
                 const float* __restrict__ xpf, const float* __restrict__ xpr,
                 const float* __restrict__ dtwf, const float* __restrict__ dtwr,
                 const float* __restrict__ dtbf, const float* __restrict__ dtbr,
                 float* __restrict__ dblf, float* __restrict__ dblr,
                 float* __restrict__ dtf, float* __restrict__ dtr) {
  const int tok = blockIdx.x;
  const int dir = blockIdx.y;
  const float* u = (dir ? ur : uf) + (size_t)tok * EDIM;
  const float* xp = dir ? xpr : xpf;
  const float* dtw = dir ? dtwr : dtwf;
  const float* dtb = dir ? dtbr : dtbf;
  float* dblo = (dir ? dblr : dblf) + (size_t)tok * XDIM;
  float* dto = (dir ? dtr : dtf) + (size_t)tok * EDIM;
  __shared__ float us[EDIM];
  __shared__ float dbls[XDIM];
  const int tid = threadIdx.x;
  for (int i = tid; i < EDIM; i += 256) us[i] = u[i];
  __syncthreads();
  const int wv = tid >> 6, ln = tid & 63;
  for (int rr = 0; rr < 14; ++rr) {     // 4 waves x 14 rows = 56
    const int row = wv * 14 + rr;
    const float* xrow = xp + (size_t)row * EDIM;
    float p = 0.f;
    #pragma unroll
    for (int j = 0; j < EDIM / 64; ++j) p += us[ln + j * 64] * xrow[ln + j * 64];
    #pragma unroll
    for (int off = 32; off; off >>= 1) p += __shfl_xor(p, off, 64);
    if (ln == 0) dbls[row] = p;
  }
  __syncthreads();
  if (tid < XDIM) dblo[tid] = dbls[tid];
  for (int e = tid; e < EDIM; e += 256) {
    float a = dtb[e];
    const float* dw = dtw + (size_t)e * RDIM;
    #pragma unroll
    for (int rj = 0; rj < RDIM; ++rj) a += dbls[rj] * dw[rj];
    dto[e] = (a > 20.f) ? a : log1pf(__expf(a));   // softplus
  }
}

// ================= chunked parallel selective scan =================
// pass 1: per-chunk summary with h_in = 0 -> P (prod of a), H (final state)
__global__ __launch_bounds__(256)
void em_scan_sum(const float* __restrict__ dtf, const float* __restrict__ dtr,
                 const float* __restrict__ uf, const float* __restrict__ ur,
                 const float* __restrict__ dblf, const float* __restrict__ dblr,
                 const float* __restrict__ Alogf, const float* __restrict__ Alogr,
                 float* __restrict__ Pfw, float* __restrict__ Prv,
                 float* __restrict__ Hfw, float* __restrict__ Hrv,
                 int L, int nchunks) {
  const int dir = blockIdx.z;
  const int n = blockIdx.y / nchunks;
  const int c = blockIdx.y % nchunks;
  const int tid = threadIdx.x;
  const int e = blockIdx.x * 256 + tid;
  const float* dt = dir ? dtr : dtf;
  const float* u = dir ? ur : uf;
  const float* dbl = dir ? dblr : dblf;
  const float* Alog = dir ? Alogr : Alogf;
  float* P = dir ? Prv : Pfw;
  float* H = dir ? Hrv : Hfw;
  const int p0 = c * CLEN;
  const int len = min(CLEN, L - p0);
  __shared__ float Bs[CLEN][SDIM];
  {
    const int j = tid >> 4, s = tid & 15;
    if (j < len) {
      const int pos = p0 + j;
      const int l = dir ? (L - 1 - pos) : pos;
      Bs[j][s] = dbl[((size_t)n * L + l) * XDIM + RDIM + s];
    }
  }
  __syncthreads();
  float A[SDIM], h[SDIM], Pp[SDIM];
  #pragma unroll
  for (int s = 0; s < SDIM; ++s) {
    A[s] = -__expf(Alog[e * SDIM + s]);
    h[s] = 0.f; Pp[s] = 1.f;
  }
  for (int j = 0; j < len; ++j) {
    const int pos = p0 + j;
    const int l = dir ? (L - 1 - pos) : pos;
    const size_t tok = (size_t)n * L + l;
    const float dtv = dt[tok * EDIM + e];
    const float dtu = dtv * u[tok * EDIM + e];
    #pragma unroll
    for (int s = 0; s < SDIM; ++s) {
      const float a = __expf(dtv * A[s]);
      h[s] = a * h[s] + dtu * Bs[j][s];
      Pp[s] *= a;
    }
  }
  const size_t base = ((size_t)(n * nchunks + c) * EDIM + e) * SDIM;
  #pragma unroll
  for (int s = 0; s < SDIM; ++s) { P[base + s] = Pp[s]; H[base + s] = h[s]; }
}

// pass 2: sequential combine over chunks; overwrites H in-place with H_in per chunk.
__global__ __launch_bounds__(256)
void em_scan_combine(const float* __restrict__ Pfw, const float* __restrict__ Prv,
                     float* __restrict__ Hfw, float* __restrict__ Hrv, int nchunks) {
  const int dir = blockIdx.z;
  const int idx = blockIdx.x * 256 + threadIdx.x;
  const int n = idx / (EDIM * SDIM);
  const int r = idx % (EDIM * SDIM);
  const float* P = dir ? Prv : Pfw;
  float* H = dir ? Hrv : Hfw;
  float h = 0.f;
  for (int c = 0; c < nchunks; ++c) {
    const size_t b = (size_t)(n * nchunks + c) * (EDIM * SDIM) + r;
    const float pv = P[b];
    const float hf = H[b];
    H[b] = h;
    h = pv * h + hf;
  }
}

// pass 3: full scan per chunk from H_in, write gated y at original positions.
__global__ __launch_bounds__(256)
void em_scan_out(const float* __restrict__ dtf, const float* __restrict__ dtr,
                 const float* __restrict__ uf, const float* __restrict__ ur,
                 const float* __restrict__ dblf, const float* __restrict__ dblr,
                 const float* __restrict__ xz,
                 const float* __restrict__ Alogf, const float* __restrict__ Alogr,
                 const float* __restrict__ Dpf, const float* __restrict__ Dpr,
                 const float* __restrict__ Hfw, const float* __restrict__ Hrv,
                 float* __restrict__ yf, float* __restrict__ yr,
                 int L, int nchunks) {
  const int dir = blockIdx.z;
  const int n = blockIdx.y / nchunks;
  const int c = blockIdx.y % nchunks;
  const int tid = threadIdx.x;
  const int e = blockIdx.x * 256 + tid;
  const float* dt = dir ? dtr : dtf;
  const float* u = dir ? ur : uf;
  const float* dbl = dir ? dblr : dblf;
  const float* Alog = dir ? Alogr : Alogf;
  const float* Dp = dir ? Dpr : Dpf;
  const float* Hin = dir ? Hrv : Hfw;
  float* y = dir ? yr : yf;
  const int p0 = c * CLEN;
  const int len = min(CLEN, L - p0);
  __shared__ float Bs[CLEN][SDIM];
  __shared__ float Cs[CLEN][SDIM];
  for (int i = tid; i < 32 * CLEN; i += 256) {
    const int j = i >> 5, v = i & 31;
    if (j < len) {
      const int pos = p0 + j;
      const int l = dir ? (L - 1 - pos) : pos;
      const float val = dbl[((size_t)n * L + l) * XDIM + RDIM + v];
      if (v < 16) Bs[j][v] = val; else Cs[j][v - 16] = val;
    }
  }
  __syncthreads();
  float A[SDIM], h[SDIM];
  const size_t base = ((size_t)(n * nchunks + c) * EDIM + e) * SDIM;
  #pragma unroll
  for (int s = 0; s < SDIM; ++s) {
    A[s] = -__expf(Alog[e * SDIM + s]);
    h[s] = Hin[base + s];
  }
  const float De = Dp[e];
  for (int j = 0; j < len; ++j) {
    const int pos = p0 + j;
    const int l = dir ? (L - 1 - pos) : pos;
    const size_t tok = (size_t)n * L + l;
    const float dtv = dt[tok * EDIM + e];
    const float uv = u[tok * EDIM + e];
    const float dtu = dtv * uv;
    float acc = 0.f;
    #pragma unroll
    for (int s = 0; s < SDIM; ++s) {
      const float a = __expf(dtv * A[s]);
      h[s] = a * h[s] + dtu * Bs[j][s];
      acc += h[s] * Cs[j][s];
    }
    const float z = xz[tok * TWOE + EDIM + e];
    y[tok * EDIM + e] = (acc + uv * De) * em_silu(z);
  }
}

extern "C" void kernel_launch(void* const* d_in, const int* in_sizes, int n_in,
                              void* d_out, int out_size, void* d_ws, size_t ws_size,
                              hipStream_t stream) {
  const float* x         = (const float*)d_in[0];
  const float* patch_w   = (const float*)d_in[1];
  const float* patch_b   = (const float*)d_in[2];
  const float* cls_tok   = (const float*)d_in[3];
  const float* pos_emb   = (const float*)d_in[4];
  const float* normf     = (const float*)d_in[5];
  const float* sp_conv_w   = (const float*)d_in[6];
  const float* sp_conv_b   = (const float*)d_in[7];
  const float* sp_xproj    = (const float*)d_in[8];
  const float* sp_dtw      = (const float*)d_in[9];
  const float* sp_dtb      = (const float*)d_in[10];
  const float* sp_Alog     = (const float*)d_in[11];
  const float* sp_D        = (const float*)d_in[12];
  const float* sp_conv_w_r = (const float*)d_in[13];
  const float* sp_conv_b_r = (const float*)d_in[14];
  const float* sp_xproj_r  = (const float*)d_in[15];
  const float* sp_dtw_r    = (const float*)d_in[16];
  const float* sp_dtb_r    = (const float*)d_in[17];
  const float* sp_Alog_r   = (const float*)d_in[18];
  const float* sp_D_r      = (const float*)d_in[19];
  const float* tm_conv_w   = (const float*)d_in[20];
  const float* tm_conv_b   = (const float*)d_in[21];
  const float* tm_xproj    = (const float*)d_in[22];
  const float* tm_dtw      = (const float*)d_in[23];
  const float* tm_dtb      = (const float*)d_in[24];
  const float* tm_Alog     = (const float*)d_in[25];
  const float* tm_D        = (const float*)d_in[26];
  const float* sp_norm     = (const float*)d_in[27];
  const float* sp_inproj   = (const float*)d_in[28];
  const float* sp_outproj  = (const float*)d_in[29];
  const float* tm_norm     = (const float*)d_in[30];
  const float* tm_inproj   = (const float*)d_in[31];
  const float* tm_outproj  = (const float*)d_in[32];

  float* ws = (float*)d_ws;
  size_t o = 0;
  float* hidden   = ws + o; o += (size_t)NTOKS * DMODEL;
  float* residual = ws + o; o += (size_t)NTOKS * DMODEL;
  float* xn       = ws + o; o += (size_t)NTOKS * DMODEL;
  float* xz       = ws + o; o += (size_t)NTOKS * TWOE;
  float* u_f      = ws + o; o += (size_t)NTOKS * EDIM;
  float* u_r      = ws + o; o += (size_t)NTOKS * EDIM;
  float* dbl_f    = ws + o; o += (size_t)NTOKS * XDIM;
  float* dbl_r    = ws + o; o += (size_t)NTOKS * XDIM;
  float* dt_f     = ws + o; o += (size_t)NTOKS * EDIM;
  float* dt_r     = ws + o; o += (size_t)NTOKS * EDIM;
  float* y_f      = ws + o; o += (size_t)NTOKS * EDIM;
  float* y_r      = ws + o; o += (size_t)NTOKS * EDIM;
  const size_t sum_elems = (size_t)208 * EDIM * SDIM;
  float* scanP_f  = ws + o; o += sum_elems;
  float* scanP_r  = ws + o; o += sum_elems;
  float* scanH_f  = ws + o; o += sum_elems;
  float* scanH_r  = ws + o; o += sum_elems;

  // patch-embed scratch aliases (u_f/u_r are unused until the first conv)
  float* im2col_buf = u_f;   // 3136 x 768 fits in 3152 x 768
  float* patch_tmp  = u_r;   // 3136 x 384

  const int L_sp = 197, NC_sp = (L_sp + CLEN - 1) / CLEN;   // 13
  const int L_tm = 1576, NC_tm = (L_tm + CLEN - 1) / CLEN;  // 99

  hipMemsetAsync(residual, 0, (size_t)NTOKS * DMODEL * sizeof(float), stream);

  // -------- patch embed as im2col + MFMA GEMM + epilogue --------
  em_im2col<<<(NPATCH * 768) / 256, 256, 0, stream>>>(x, im2col_buf);
  em_gemm_bf16<<<dim3(DMODEL / TN, (NPATCH + TM - 1) / TM), 256, 0, stream>>>(
      im2col_buf, nullptr, patch_w, patch_tmp, NPATCH, DMODEL, 768);
  em_embed_final<<<NTOKS, DMODEL, 0, stream>>>(patch_tmp, patch_b, cls_tok, pos_emb, hidden);

  // -------- 12 spatial bimamba blocks: N=16 sequences of L=197 --------
  for (int i = 0; i < NLAYER; ++i) {
    em_add_rmsnorm<<<NTOKS, DMODEL, 0, stream>>>(hidden, residual, residual,
                                                 sp_norm + (size_t)i * DMODEL, xn);
    em_gemm_bf16<<<dim3(TWOE / TN, (NTOKS + TM - 1) / TM), 256, 0, stream>>>(
        xn, nullptr, sp_inproj + (size_t)i * TWOE * DMODEL, xz, NTOKS, TWOE, DMODEL);
    em_conv_silu<<<dim3(EDIM / 256, NTOKS, 2), 256, 0, stream>>>(
        xz, sp_conv_w + (size_t)i * EDIM * 4, sp_conv_b + (size_t)i * EDIM,
        sp_conv_w_r + (size_t)i * EDIM * 4, sp_conv_b_r + (size_t)i * EDIM, u_f, u_r, L_sp);
    em_xproj_dt<<<dim3(NTOKS, 2), 256, 0, stream>>>(
        u_f, u_r, sp_xproj + (size_t)i * XDIM * EDIM, sp_xproj_r + (size_t)i * XDIM * EDIM,
        sp_dtw + (size_t)i * EDIM * RDIM, sp_dtw_r + (size_t)i * EDIM * RDIM,
        sp_dtb + (size_t)i * EDIM, sp_dtb_r + (size_t)i * EDIM, dbl_f, dbl_r, dt_f, dt_r);
    em_scan_sum<<<dim3(EDIM / 256, 16 * NC_sp, 2), 256, 0, stream>>>(
        dt_f, dt_r, u_f, u_r, dbl_f, dbl_r,
        sp_Alog + (size_t)i * EDIM * SDIM, sp_Alog_r + (size_t)i * EDIM * SDIM,
        scanP_f, scanP_r, scanH_f, scanH_r, L_sp, NC_sp);
    em_scan_combine<<<dim3(16 * EDIM * SDIM / 256, 1, 2), 256, 0, stream>>>(
        scanP_f, scanP_r, scanH_f, scanH_r, NC_sp);
    em_scan_out<<<dim3(EDIM / 256, 16 * NC_sp, 2), 256, 0, stream>>>(
        dt_f, dt_r, u_f, u_r, dbl_f, dbl_r, xz,
        sp_Alog + (size_t)i * EDIM * SDIM, sp_Alog_r + (size_t)i * EDIM * SDIM,
        sp_D + (size_t)i * EDIM, sp_D_r + (size_t)i * EDIM,
        scanH_f, scanH_r, y_f, y_r, L_sp, NC_sp);
    em_gemm_bf16<<<dim3(DMODEL / TN, (NTOKS + TM - 1) / TM), 256, 0, stream>>>(
        y_f, y_r, sp_outproj + (size_t)i * DMODEL * EDIM, hidden, NTOKS, DMODEL, EDIM);
  }

  // -------- 12 temporal mamba blocks: N=2 sequences of L=1576 --------
  for (int i = 0; i < NLAYER; ++i) {
    em_add_rmsnorm<<<NTOKS, DMODEL, 0, stream>>>(hidden, residual, residual,
                                                 tm_norm + (size_t)i * DMODEL, xn);
    em_gemm_bf16<<<dim3(TWOE / TN, (NTOKS + TM - 1) / TM), 256, 0, stream>>>(
        xn, nullptr, tm_inproj + (size_t)i * TWOE * DMODEL, xz, NTOKS, TWOE, DMODEL);
    em_conv_silu<<<dim3(EDIM / 256, NTOKS, 1), 256, 0, stream>>>(
        xz, tm_conv_w + (size_t)i * EDIM * 4, tm_conv_b + (size_t)i * EDIM,
        tm_conv_w + (size_t)i * EDIM * 4, tm_conv_b + (size_t)i * EDIM, u_f, u_r, L_tm);
    em_xproj_dt<<<dim3(NTOKS, 1), 256, 0, stream>>>(
        u_f, u_r, tm_xproj + (size_t)i * XDIM * EDIM, tm_xproj + (size_t)i * XDIM * EDIM,
        tm_dtw + (size_t)i * EDIM * RDIM, tm_dtw + (size_t)i * EDIM * RDIM,
        tm_dtb + (size_t)i * EDIM, tm_dtb + (size_t)i * EDIM, dbl_f, dbl_r, dt_f, dt_r);
    em_scan_sum<<<dim3(EDIM / 256, 2 * NC_tm, 1), 256, 0, stream>>>(
        dt_f, dt_r, u_f, u_r, dbl_f, dbl_r,
        tm_Alog + (size_t)i * EDIM * SDIM, tm_Alog + (size_t)i * EDIM * SDIM,
        scanP_f, scanP_r, scanH_f, scanH_r, L_tm, NC_tm);
    em_scan_combine<<<dim3(2 * EDIM * SDIM / 256, 1, 1), 256, 0, stream>>>(
        scanP_f, scanP_r, scanH_f, scanH_r, NC_tm);
    em_scan_out<<<dim3(EDIM / 256, 2 * NC_tm, 1), 256, 0, stream>>>(
        dt_f, dt_r, u_f, u_r, dbl_f, dbl_r, xz,
        tm_Alog + (size_t)i * EDIM * SDIM, tm_Alog + (size_t)i * EDIM * SDIM,
        tm_D + (size_t)i * EDIM, tm_D + (size_t)i * EDIM,
        scanH_f, scanH_r, y_f, y_r, L_tm, NC_tm);
    em_gemm_bf16<<<dim3(DMODEL / TN, (NTOKS + TM - 1) / TM), 256, 0, stream>>>(
        y_f, nullptr, tm_outproj + (size_t)i * DMODEL * EDIM, hidden, NTOKS, DMODEL, EDIM);
  }

  // -------- final: rmsnorm(hidden + residual) * normf -> d_out --------
  em_add_rmsnorm<<<NTOKS, DMODEL, 0, stream>>>(hidden, residual, nullptr, normf, (float*)d_out);
}